// Round 1
// baseline (525.482 us; speedup 1.0000x reference)
//
#include <hip/hip_runtime.h>
#include <math.h>

#define B_ 512
#define C_ 100000
#define D_ 128
#define BT 128
#define CT 128
#define DK 32
#define LSTR 36                        // LDS row stride (floats): 144B, 16B-aligned, breaks pow2 banks
#define NGROUPS 196
#define NTILES ((C_ + CT - 1) / CT)    // 782

// --- kernel 0/1: per-row L2 norm stats (one wave per row) ---------------------
__global__ __launch_bounds__(256) void row_norm_kernel(
    const float* __restrict__ in, int nrows,
    float* __restrict__ out_vec,   // nullable: 3 * normalized row
    float* __restrict__ out_inv,   // nullable: 3 / max(||row||, eps)
    float* __restrict__ out_sq)    // nullable: ||scaled row||^2
{
  int lane = threadIdx.x & 63;
  int wv   = threadIdx.x >> 6;
  int r = blockIdx.x * 4 + wv;
  if (r >= nrows) return;
  const float* row = in + (size_t)r * D_;
  float2 v = *(const float2*)(row + lane * 2);
  float ss = v.x * v.x + v.y * v.y;
#pragma unroll
  for (int off = 32; off >= 1; off >>= 1) ss += __shfl_xor(ss, off);
  float n   = sqrtf(ss);
  float den = fmaxf(n, 1e-12f);
  float inv = 3.0f / den;
  if (out_vec) {
    float2 o; o.x = v.x * inv; o.y = v.y * inv;
    *(float2*)(out_vec + (size_t)r * D_ + lane * 2) = o;
  }
  if (lane == 0) {
    if (out_inv) out_inv[r] = inv;
    if (out_sq)  { float t = inv * n; out_sq[r] = t * t; }
  }
}

// --- kernel 2: fused GEMM + online masked logsumexp ---------------------------
// grid = (NGROUPS, B_/BT), block = 256.
// thread (tx,ty): tx=tid&15 (c dir), ty=tid>>4 (b dir); 8x8 micro-tile:
//   b = b0 + ty + 16*i,  c = c0 + tx + 16*j
__global__ __launch_bounds__(256) void pnca_main_kernel(
    const float* __restrict__ xn, const float* __restrict__ x2,
    const float* __restrict__ praw, const float* __restrict__ invn,
    const float* __restrict__ p2, const int* __restrict__ labels,
    float* __restrict__ posd, float* __restrict__ pm, float* __restrict__ psum)
{
  __shared__ float xs[BT * LSTR];
  __shared__ float ph[CT * LSTR];
  __shared__ float p2s[CT];

  const int tid = threadIdx.x;
  const int tx = tid & 15;
  const int ty = tid >> 4;
  const int b0 = blockIdx.y * BT;

  float x2r[8]; int lab[8];
#pragma unroll
  for (int i = 0; i < 8; ++i) {
    int b = b0 + ty + 16 * i;
    x2r[i] = x2[b];
    lab[i] = labels[b];
  }
  float mrun[8], srun[8];
#pragma unroll
  for (int i = 0; i < 8; ++i) { mrun[i] = -INFINITY; srun[i] = 0.f; }

  for (int t = blockIdx.x; t < NTILES; t += NGROUPS) {
    const int c0 = t * CT;
    float acc[8][8];
#pragma unroll
    for (int i = 0; i < 8; ++i)
#pragma unroll
      for (int j = 0; j < 8; ++j) acc[i][j] = 0.f;

    if (tid < CT) {
      int c = c0 + tid;
      p2s[tid] = (c < C_) ? p2[c] : 0.f;
    }

    for (int dk = 0; dk < D_; dk += DK) {
      __syncthreads();
      // stage x tile: 128 rows x 32 cols (f32), 1024 float4s, 4 per thread
#pragma unroll
      for (int k = 0; k < 4; ++k) {
        int f = tid + k * 256;
        int r = f >> 3, c4 = f & 7;
        float4 v = *(const float4*)(xn + (size_t)(b0 + r) * D_ + dk + c4 * 4);
        *(float4*)(xs + r * LSTR + c4 * 4) = v;
      }
      // stage p tile, scaled by invn on the fly
#pragma unroll
      for (int k = 0; k < 4; ++k) {
        int f = tid + k * 256;
        int r = f >> 3, c4 = f & 7;
        int c = c0 + r;
        float4 v = make_float4(0.f, 0.f, 0.f, 0.f);
        float sc = 0.f;
        if (c < C_) {
          v = *(const float4*)(praw + (size_t)c * D_ + dk + c4 * 4);
          sc = invn[c];
        }
        v.x *= sc; v.y *= sc; v.z *= sc; v.w *= sc;
        *(float4*)(ph + r * LSTR + c4 * 4) = v;
      }
      __syncthreads();
#pragma unroll
      for (int d4 = 0; d4 < DK / 4; ++d4) {
        float4 xf[8], pf[8];
#pragma unroll
        for (int i = 0; i < 8; ++i)
          xf[i] = *(const float4*)(xs + (ty + 16 * i) * LSTR + d4 * 4);
#pragma unroll
        for (int j = 0; j < 8; ++j)
          pf[j] = *(const float4*)(ph + (tx + 16 * j) * LSTR + d4 * 4);
#pragma unroll
        for (int i = 0; i < 8; ++i)
#pragma unroll
          for (int j = 0; j < 8; ++j) {
            acc[i][j] = fmaf(xf[i].x, pf[j].x, acc[i][j]);
            acc[i][j] = fmaf(xf[i].y, pf[j].y, acc[i][j]);
            acc[i][j] = fmaf(xf[i].z, pf[j].z, acc[i][j]);
            acc[i][j] = fmaf(xf[i].w, pf[j].w, acc[i][j]);
          }
      }
    }

    // scores + online lse update (exclude positive class, record its dist)
#pragma unroll
    for (int j = 0; j < 8; ++j) {
      int c = c0 + tx + 16 * j;
      bool valid = (c < C_);
      float pp = p2s[tx + 16 * j];
#pragma unroll
      for (int i = 0; i < 8; ++i) {
        if (valid) {
          float nd = 2.f * acc[i][j] - x2r[i] - pp;   // = -dist
          if (c == lab[i]) {
            posd[b0 + ty + 16 * i] = -nd;
          } else {
            float mn = fmaxf(mrun[i], nd);
            srun[i] = srun[i] * __expf(mrun[i] - mn) + __expf(nd - mn);
            mrun[i] = mn;
          }
        }
      }
    }
    __syncthreads();   // protect p2s before next tile's staging
  }

  // cross-tx (16-lane) reduce of (m,s), write per-group partials
#pragma unroll
  for (int i = 0; i < 8; ++i) {
    float m = mrun[i], s = srun[i];
#pragma unroll
    for (int off = 1; off < 16; off <<= 1) {
      float mo = __shfl_xor(m, off);
      float so = __shfl_xor(s, off);
      float mn = fmaxf(m, mo);
      float sn = (mn == -INFINITY) ? 0.f
                 : s * __expf(m - mn) + so * __expf(mo - mn);
      m = mn; s = sn;
    }
    if (tx == 0) {
      size_t idx = (size_t)blockIdx.x * B_ + (b0 + ty + 16 * i);
      pm[idx] = m; psum[idx] = s;
    }
  }
}

// --- kernel 3: combine partials, lse, mean ------------------------------------
__global__ __launch_bounds__(512) void finalize_kernel(
    const float* __restrict__ pm, const float* __restrict__ psum,
    const float* __restrict__ posd, float* __restrict__ out)
{
  int b = threadIdx.x;
  float m = -INFINITY, s = 0.f;
  for (int g = 0; g < NGROUPS; ++g) {
    float mo = pm[(size_t)g * B_ + b];
    float so = psum[(size_t)g * B_ + b];
    float mn = fmaxf(m, mo);
    s = (mn == -INFINITY) ? 0.f : s * __expf(m - mn) + so * __expf(mo - mn);
    m = mn;
  }
  float val = posd[b] + m + logf(s);
#pragma unroll
  for (int off = 1; off < 64; off <<= 1) val += __shfl_xor(val, off);
  __shared__ float red[8];
  int lane = b & 63, wv = b >> 6;
  if (lane == 0) red[wv] = val;
  __syncthreads();
  if (b == 0) {
    float tot = 0.f;
    for (int w = 0; w < 8; ++w) tot += red[w];
    out[0] = tot / (float)B_;
  }
}

extern "C" void kernel_launch(void* const* d_in, const int* in_sizes, int n_in,
                              void* d_out, int out_size, void* d_ws, size_t ws_size,
                              hipStream_t stream)
{
  const float* batch   = (const float*)d_in[0];
  const int*   labels  = (const int*)d_in[1];
  const float* proxies = (const float*)d_in[2];
  float* out = (float*)d_out;
  float* ws  = (float*)d_ws;

  float* xn   = ws;                               // 512*128
  float* x2   = xn   + (size_t)B_ * D_;           // 512
  float* invn = x2   + B_;                        // 100000
  float* p2   = invn + C_;                        // 100000
  float* posd = p2   + C_;                        // 512
  float* pm   = posd + B_;                        // 196*512
  float* psum = pm   + (size_t)NGROUPS * B_;      // 196*512

  row_norm_kernel<<<B_ / 4, 256, 0, stream>>>(batch, B_, xn, nullptr, x2);
  row_norm_kernel<<<(C_ + 3) / 4, 256, 0, stream>>>(proxies, C_, nullptr, invn, p2);

  dim3 grid(NGROUPS, B_ / BT);
  pnca_main_kernel<<<grid, 256, 0, stream>>>(xn, x2, proxies, invn, p2, labels,
                                             posd, pm, psum);
  finalize_kernel<<<1, B_, 0, stream>>>(pm, psum, posd, out);
}

// Round 2
// 167.355 us; speedup vs baseline: 3.1399x; 3.1399x over previous
//
#include <hip/hip_runtime.h>
#include <math.h>

#define B_ 512
#define C_ 100000
#define D_ 128
#define CT 192
#define NBLK ((C_ + CT - 1) / CT)   // 521 blocks over proxy columns
#define G_ (NBLK * 2)               // 1042 partials per batch row (2 col-half waves/block)
#define LSTR 136                    // LDS row stride in bf16 elems: 272B -> 2-way banks (free)

typedef __attribute__((ext_vector_type(8))) short short8;  // 8 bf16 = 4 VGPRs (MFMA A/B frag)
typedef __attribute__((ext_vector_type(4))) float f32x4;   // MFMA C/D frag

__device__ __forceinline__ float b2f(unsigned short u) {
  union { float f; unsigned int i; } v; v.i = ((unsigned int)u) << 16; return v.f;
}
__device__ __forceinline__ unsigned short f2b(float x) {  // RNE f32->bf16
  union { float f; unsigned int i; } v; v.f = x;
  unsigned int r = v.i + 0x7FFFu + ((v.i >> 16) & 1u);
  return (unsigned short)(r >> 16);
}

// --- kernel A: normalize batch rows to norm 3, store bf16 ---------------------
__global__ __launch_bounds__(256) void batch_norm_kernel(
    const float* __restrict__ batch, unsigned short* __restrict__ xnb)
{
  int lane = threadIdx.x & 63, wv = threadIdx.x >> 6;
  int r = blockIdx.x * 4 + wv;               // grid=128 -> 512 rows
  float2 v = *(const float2*)(batch + (size_t)r * D_ + lane * 2);
  float ss = v.x * v.x + v.y * v.y;
#pragma unroll
  for (int off = 32; off; off >>= 1) ss += __shfl_xor(ss, off);
  float sc = 3.f / fmaxf(sqrtf(ss), 1e-12f);
  ushort2 o; o.x = f2b(v.x * sc); o.y = f2b(v.y * sc);
  *(ushort2*)(xnb + (size_t)r * D_ + lane * 2) = o;
}

// --- main kernel: fused proxy-norm + bf16 MFMA scores + exp row-sums ----------
// grid = NBLK (proxy tiles of 192), block = 256 (4 waves: wm=w&1 rows, wn=w>>1 cols)
__global__ __launch_bounds__(256) void pnca_main_kernel(
    const float* __restrict__ praw, const unsigned short* __restrict__ xnb,
    float* __restrict__ pt)
{
  __shared__ unsigned short plds[CT * LSTR];   // raw proxies, bf16
  __shared__ float scs[CT];                    // 3 / ||p_row||

  const int tid  = threadIdx.x;
  const int lane = tid & 63;
  const int w    = tid >> 6;
  const int wm   = w & 1;
  const int wn   = w >> 1;
  const int c0   = blockIdx.x * CT;

  // stage P tile (raw bf16) + per-row norms; one wave per row, deterministic reduce
  for (int r = w; r < CT; r += 4) {
    int c = c0 + r;
    float2 v = make_float2(0.f, 0.f);
    if (c < C_) v = *(const float2*)(praw + (size_t)c * D_ + lane * 2);
    float ss = v.x * v.x + v.y * v.y;
#pragma unroll
    for (int off = 32; off; off >>= 1) ss += __shfl_xor(ss, off);
    ushort2 o; o.x = f2b(v.x); o.y = f2b(v.y);
    *(ushort2*)(plds + r * LSTR + lane * 2) = o;
    if (lane == 0) scs[r] = 3.f / fmaxf(sqrtf(ss), 1e-12f);
  }
  __syncthreads();

  // per-lane column constants: nd = acc*(2*3*sc/... ) folded: acc*s2 + q
  float s2[6], qn[6];
#pragma unroll
  for (int n = 0; n < 6; ++n) {
    int cl = wn * 96 + n * 16 + (lane & 15);
    s2[n] = 2.f * scs[cl];                       // dot_normalized = acc * sc ; nd = 2*dot - 18
    qn[n] = (c0 + cl < C_) ? -18.f : -1e30f;     // OOB cols contribute exp(-1e30)=0
  }

  const int g = blockIdx.x * 2 + wn;

  for (int bt = 0; bt < 4; ++bt) {
    const int rbase = bt * 128 + wm * 64;
    f32x4 acc[4][6];
#pragma unroll
    for (int m = 0; m < 4; ++m)
#pragma unroll
      for (int n = 0; n < 6; ++n) acc[m][n] = (f32x4){0.f, 0.f, 0.f, 0.f};

#pragma unroll
    for (int ks = 0; ks < 4; ++ks) {
      const int ko = ks * 32 + (lane >> 4) * 8;
      short8 a[4];
#pragma unroll
      for (int m = 0; m < 4; ++m)
        a[m] = *(const short8*)(xnb + (size_t)(rbase + m * 16 + (lane & 15)) * D_ + ko);
      short8 b[6];
#pragma unroll
      for (int n = 0; n < 6; ++n)
        b[n] = *(const short8*)(plds + (wn * 96 + n * 16 + (lane & 15)) * LSTR + ko);
#pragma unroll
      for (int m = 0; m < 4; ++m)
#pragma unroll
        for (int n = 0; n < 6; ++n)
          acc[m][n] = __builtin_amdgcn_mfma_f32_16x16x32_bf16(a[m], b[n], acc[m][n], 0, 0, 0);
    }

    // epilogue: exp(-dist) row-sums; C/D layout: col=lane&15, row=(lane>>4)*4+reg
#pragma unroll
    for (int m = 0; m < 4; ++m) {
      float srow[4] = {0.f, 0.f, 0.f, 0.f};
#pragma unroll
      for (int n = 0; n < 6; ++n) {
#pragma unroll
        for (int r = 0; r < 4; ++r) {
          float nd = fmaf(acc[m][n][r], s2[n], qn[n]);
          srow[r] += __expf(nd);
        }
      }
#pragma unroll
      for (int r = 0; r < 4; ++r) {
        float s = srow[r];
#pragma unroll
        for (int off = 1; off < 16; off <<= 1) s += __shfl_xor(s, off);
        if ((lane & 15) == 0) {
          int row = rbase + m * 16 + (lane >> 4) * 4 + r;
          pt[(size_t)row * G_ + g] = s;
        }
      }
    }
  }
}

// --- kernel E: per-row combine + positive distance + loss ---------------------
__global__ __launch_bounds__(256) void finalize_rows_kernel(
    const float* __restrict__ praw, const unsigned short* __restrict__ xnb,
    const int* __restrict__ labels, const float* __restrict__ pt,
    float* __restrict__ lossb)
{
  int lane = threadIdx.x & 63, wv = threadIdx.x >> 6;
  int row = blockIdx.x * 4 + wv;             // grid=128 -> 512 rows
  int lab = labels[row];
  float2 pv = *(const float2*)(praw + (size_t)lab * D_ + lane * 2);
  ushort2 xv = *(const ushort2*)(xnb + (size_t)row * D_ + lane * 2);
  float xa = b2f(xv.x), xb = b2f(xv.y);
  float ssp = pv.x * pv.x + pv.y * pv.y;
  float dp  = xa * pv.x + xb * pv.y;
#pragma unroll
  for (int off = 32; off; off >>= 1) {
    ssp += __shfl_xor(ssp, off);
    dp  += __shfl_xor(dp, off);
  }
  float pd = 18.f - 2.f * dp * (3.f / fmaxf(sqrtf(ssp), 1e-12f));  // positive dist (f32-ish)
  float s = 0.f;
  for (int gg = lane; gg < G_; gg += 64) s += pt[(size_t)row * G_ + gg];
#pragma unroll
  for (int off = 32; off; off >>= 1) s += __shfl_xor(s, off);
  if (lane == 0) lossb[row] = pd + logf(s - __expf(-pd));
}

// --- kernel F: mean over 512 rows ---------------------------------------------
__global__ __launch_bounds__(512) void reduce_mean_kernel(
    const float* __restrict__ lossb, float* __restrict__ out)
{
  int t = threadIdx.x;
  float v = lossb[t];
#pragma unroll
  for (int off = 1; off < 64; off <<= 1) v += __shfl_xor(v, off);
  __shared__ float red[8];
  if ((t & 63) == 0) red[t >> 6] = v;
  __syncthreads();
  if (t == 0) {
    float tot = 0.f;
    for (int i = 0; i < 8; ++i) tot += red[i];
    out[0] = tot / (float)B_;
  }
}

extern "C" void kernel_launch(void* const* d_in, const int* in_sizes, int n_in,
                              void* d_out, int out_size, void* d_ws, size_t ws_size,
                              hipStream_t stream)
{
  const float* batch   = (const float*)d_in[0];
  const int*   labels  = (const int*)d_in[1];
  const float* proxies = (const float*)d_in[2];
  float* out = (float*)d_out;

  unsigned short* xnb = (unsigned short*)d_ws;                       // 512*128*2 = 128KB
  float* pt    = (float*)((char*)d_ws + 131072);                     // 512*1042*4 ~= 2.13MB
  float* lossb = (float*)((char*)d_ws + 131072 + (size_t)B_ * G_ * 4);

  batch_norm_kernel<<<B_ / 4, 256, 0, stream>>>(batch, xnb);
  pnca_main_kernel<<<NBLK, 256, 0, stream>>>(proxies, xnb, pt);
  finalize_rows_kernel<<<B_ / 4, 256, 0, stream>>>(proxies, xnb, labels, pt, lossb);
  reduce_mean_kernel<<<1, 512, 0, stream>>>(lossb, out);
}

// Round 3
// 121.121 us; speedup vs baseline: 4.3385x; 1.3817x over previous
//
#include <hip/hip_runtime.h>
#include <math.h>

#define B_ 512
#define C_ 100000
#define D_ 128
#define CT 128                       // proxy cols per block
#define NBLK ((C_ + CT - 1) / CT)    // 782
#define G_ NBLK
#define LOG2E 1.4426950408889634f

typedef __attribute__((ext_vector_type(8))) short short8;  // 8 bf16 (MFMA A/B frag)
typedef __attribute__((ext_vector_type(4))) float f32x4;   // MFMA C/D frag

__device__ __forceinline__ unsigned short f2b(float x) {  // RNE f32->bf16
  union { float f; unsigned int i; } v; v.f = x;
  unsigned int r = v.i + 0x7FFFu + ((v.i >> 16) & 1u);
  return (unsigned short)(r >> 16);
}
__device__ __forceinline__ float b2f(unsigned short u) {
  union { float f; unsigned int i; } v; v.i = ((unsigned int)u) << 16; return v.f;
}

#if defined(__has_builtin)
#if __has_builtin(__builtin_amdgcn_exp2f)
#define EXP2F(x) __builtin_amdgcn_exp2f(x)
#endif
#endif
#ifndef EXP2F
#define EXP2F(x) __expf(0.69314718055994531f * (x))
#endif

// --- kernel A: normalize batch rows to norm 3, store bf16 ---------------------
__global__ __launch_bounds__(256) void batch_norm_kernel(
    const float* __restrict__ batch, unsigned short* __restrict__ xnb)
{
  int lane = threadIdx.x & 63, wv = threadIdx.x >> 6;
  int r = blockIdx.x * 4 + wv;               // grid=128 -> 512 rows
  float2 v = *(const float2*)(batch + (size_t)r * D_ + lane * 2);
  float ss = v.x * v.x + v.y * v.y;
#pragma unroll
  for (int off = 32; off; off >>= 1) ss += __shfl_xor(ss, off);
  float sc = 3.f / fmaxf(sqrtf(ss), 1e-12f);
  ushort2 o; o.x = f2b(v.x * sc); o.y = f2b(v.y * sc);
  *(ushort2*)(xnb + (size_t)r * D_ + lane * 2) = o;
}

// --- main kernel: register-resident B frags, no staging barrier ---------------
// grid = NBLK, block = 256 (4 waves). Wave w owns cols [c0+w*32, +32), all rows.
__global__ __launch_bounds__(256, 3) void pnca_main_kernel(
    const float* __restrict__ praw, const unsigned short* __restrict__ xnb,
    float* __restrict__ pt)
{
  __shared__ float ldsred[128][4];

  const int lane = threadIdx.x & 63;
  const int w    = threadIdx.x >> 6;
  const int ll   = lane & 15;
  const int lq   = lane >> 4;
  const int c0   = blockIdx.x * CT;

  // ---- load this wave's B frags (raw bf16) + column sq-norms (in-register)
  short8 bf[2][4];        // [n][ks]
  float s2[2], qn[2];
#pragma unroll
  for (int n = 0; n < 2; ++n) {
    int c = c0 + w * 32 + n * 16 + ll;
    const float* rp = praw + (size_t)(c < C_ ? c : C_ - 1) * D_;
    float ss = 0.f;
#pragma unroll
    for (int ks = 0; ks < 4; ++ks) {
      float4 v0 = *(const float4*)(rp + ks * 32 + lq * 8);
      float4 v1 = *(const float4*)(rp + ks * 32 + lq * 8 + 4);
      ss += v0.x * v0.x + v0.y * v0.y + v0.z * v0.z + v0.w * v0.w
          + v1.x * v1.x + v1.y * v1.y + v1.z * v1.z + v1.w * v1.w;
      short8 bb;
      bb[0] = (short)f2b(v0.x); bb[1] = (short)f2b(v0.y);
      bb[2] = (short)f2b(v0.z); bb[3] = (short)f2b(v0.w);
      bb[4] = (short)f2b(v1.x); bb[5] = (short)f2b(v1.y);
      bb[6] = (short)f2b(v1.z); bb[7] = (short)f2b(v1.w);
      bf[n][ks] = bb;
    }
    // complete the row norm across the 4 k-groups (lanes ^16, ^32 share ll)
    ss += __shfl_xor(ss, 16);
    ss += __shfl_xor(ss, 32);
    s2[n] = 6.f * LOG2E / fmaxf(sqrtf(ss), 1e-12f);   // nd' = acc*s2 + qn (log2 units)
    qn[n] = (c < C_) ? (-18.f * LOG2E) : -1e30f;      // OOB col -> exp2 = 0
  }

  // ---- 4 batch tiles of 128 rows; B frags stay in registers
  for (int bt = 0; bt < 4; ++bt) {
    const int rbase = bt * 128;
    f32x4 acc[8][2];
#pragma unroll
    for (int m = 0; m < 8; ++m) {
      acc[m][0] = (f32x4){0.f, 0.f, 0.f, 0.f};
      acc[m][1] = (f32x4){0.f, 0.f, 0.f, 0.f};
    }
#pragma unroll
    for (int ks = 0; ks < 4; ++ks) {
      const int ko = ks * 32 + lq * 8;
#pragma unroll
      for (int m = 0; m < 8; ++m) {
        short8 a = *(const short8*)(xnb + (size_t)(rbase + m * 16 + ll) * D_ + ko);
        acc[m][0] = __builtin_amdgcn_mfma_f32_16x16x32_bf16(a, bf[0][ks], acc[m][0], 0, 0, 0);
        acc[m][1] = __builtin_amdgcn_mfma_f32_16x16x32_bf16(a, bf[1][ks], acc[m][1], 0, 0, 0);
      }
    }
    __syncthreads();   // ldsred free from previous bt's readers
    // epilogue: exp2 row-sums over this wave's 32 cols; C/D: col=ll, row=lq*4+r
#pragma unroll
    for (int m = 0; m < 8; ++m) {
      float srow[4] = {0.f, 0.f, 0.f, 0.f};
#pragma unroll
      for (int n = 0; n < 2; ++n)
#pragma unroll
        for (int r = 0; r < 4; ++r)
          srow[r] += EXP2F(fmaf(acc[m][n][r], s2[n], qn[n]));
#pragma unroll
      for (int r = 0; r < 4; ++r) {
        float s = srow[r];
        s += __shfl_xor(s, 1);
        s += __shfl_xor(s, 2);
        s += __shfl_xor(s, 4);
        s += __shfl_xor(s, 8);
        if (ll == 0) ldsred[m * 16 + lq * 4 + r][w] = s;
      }
    }
    __syncthreads();
    if (threadIdx.x < 128) {
      float s = ldsred[threadIdx.x][0] + ldsred[threadIdx.x][1]
              + ldsred[threadIdx.x][2] + ldsred[threadIdx.x][3];
      pt[(size_t)(rbase + threadIdx.x) * G_ + blockIdx.x] = s;
    }
  }
}

// --- kernel E: per-row combine + positive distance + loss ---------------------
__global__ __launch_bounds__(256) void finalize_rows_kernel(
    const float* __restrict__ praw, const unsigned short* __restrict__ xnb,
    const int* __restrict__ labels, const float* __restrict__ pt,
    float* __restrict__ lossb)
{
  int lane = threadIdx.x & 63, wv = threadIdx.x >> 6;
  int row = blockIdx.x * 4 + wv;             // grid=128 -> 512 rows
  int lab = labels[row];
  float2 pv = *(const float2*)(praw + (size_t)lab * D_ + lane * 2);
  ushort2 xv = *(const ushort2*)(xnb + (size_t)row * D_ + lane * 2);
  float xa = b2f(xv.x), xb = b2f(xv.y);
  float ssp = pv.x * pv.x + pv.y * pv.y;
  float dp  = xa * pv.x + xb * pv.y;
#pragma unroll
  for (int off = 32; off; off >>= 1) {
    ssp += __shfl_xor(ssp, off);
    dp  += __shfl_xor(dp, off);
  }
  float pd = 18.f - 2.f * dp * (3.f / fmaxf(sqrtf(ssp), 1e-12f));  // positive dist
  float s = 0.f;
  for (int gg = lane; gg < G_; gg += 64) s += pt[(size_t)row * G_ + gg];
#pragma unroll
  for (int off = 32; off; off >>= 1) s += __shfl_xor(s, off);
  if (lane == 0) lossb[row] = pd + logf(s - __expf(-pd));
}

// --- kernel F: mean over 512 rows ---------------------------------------------
__global__ __launch_bounds__(512) void reduce_mean_kernel(
    const float* __restrict__ lossb, float* __restrict__ out)
{
  int t = threadIdx.x;
  float v = lossb[t];
#pragma unroll
  for (int off = 1; off < 64; off <<= 1) v += __shfl_xor(v, off);
  __shared__ float red[8];
  if ((t & 63) == 0) red[t >> 6] = v;
  __syncthreads();
  if (t == 0) {
    float tot = 0.f;
    for (int i = 0; i < 8; ++i) tot += red[i];
    out[0] = tot / (float)B_;
  }
}

extern "C" void kernel_launch(void* const* d_in, const int* in_sizes, int n_in,
                              void* d_out, int out_size, void* d_ws, size_t ws_size,
                              hipStream_t stream)
{
  const float* batch   = (const float*)d_in[0];
  const int*   labels  = (const int*)d_in[1];
  const float* proxies = (const float*)d_in[2];
  float* out = (float*)d_out;

  unsigned short* xnb = (unsigned short*)d_ws;                   // 512*128*2 = 128KB
  float* pt    = (float*)((char*)d_ws + 131072);                 // 512*782*4 ~= 1.6MB
  float* lossb = (float*)((char*)d_ws + 131072 + (size_t)B_ * G_ * 4);

  batch_norm_kernel<<<B_ / 4, 256, 0, stream>>>(batch, xnb);
  pnca_main_kernel<<<NBLK, 256, 0, stream>>>(proxies, xnb, pt);
  finalize_rows_kernel<<<B_ / 4, 256, 0, stream>>>(proxies, xnb, labels, pt, lossb);
  reduce_mean_kernel<<<1, 512, 0, stream>>>(lossb, out);
}

// Round 4
// 116.586 us; speedup vs baseline: 4.5072x; 1.0389x over previous
//
#include <hip/hip_runtime.h>
#include <math.h>

#define B_ 512
#define C_ 100000
#define D_ 128
#define CT 128                       // proxy cols per block
#define NBLK ((C_ + CT - 1) / CT)    // 782
#define G_ NBLK
#define LOG2E 1.4426950408889634f

typedef __attribute__((ext_vector_type(8))) short short8;  // 8 bf16 (MFMA A/B frag)
typedef __attribute__((ext_vector_type(4))) float f32x4;   // MFMA C/D frag

__device__ __forceinline__ unsigned short f2b(float x) {  // RNE f32->bf16
  union { float f; unsigned int i; } v; v.f = x;
  unsigned int r = v.i + 0x7FFFu + ((v.i >> 16) & 1u);
  return (unsigned short)(r >> 16);
}
__device__ __forceinline__ float b2f(unsigned short u) {
  union { float f; unsigned int i; } v; v.i = ((unsigned int)u) << 16; return v.f;
}

#if defined(__has_builtin)
#if __has_builtin(__builtin_amdgcn_exp2f)
#define EXP2F(x) __builtin_amdgcn_exp2f(x)
#endif
#endif
#ifndef EXP2F
#define EXP2F(x) __expf(0.69314718055994531f * (x))
#endif

// --- kernel A: normalize batch rows to norm 3, store bf16 ---------------------
__global__ __launch_bounds__(256) void batch_norm_kernel(
    const float* __restrict__ batch, unsigned short* __restrict__ xnb)
{
  int lane = threadIdx.x & 63, wv = threadIdx.x >> 6;
  int r = blockIdx.x * 4 + wv;               // grid=128 -> 512 rows
  float2 v = *(const float2*)(batch + (size_t)r * D_ + lane * 2);
  float ss = v.x * v.x + v.y * v.y;
#pragma unroll
  for (int off = 32; off; off >>= 1) ss += __shfl_xor(ss, off);
  float sc = 3.f / fmaxf(sqrtf(ss), 1e-12f);
  ushort2 o; o.x = f2b(v.x * sc); o.y = f2b(v.y * sc);
  *(ushort2*)(xnb + (size_t)r * D_ + lane * 2) = o;
}

// --- main kernel: grid (NBLK, 4), block 512 (8 waves) --------------------------
// wave w: wn = w&3 (32-col group), wm = w>>2 (64-row half). Each wave:
// 64 rows x 32 cols, acc[4][2], B-frags register-resident, A streamed from L2.
__global__ __launch_bounds__(512, 4) void pnca_main_kernel(
    const float* __restrict__ praw, const unsigned short* __restrict__ xnb,
    float* __restrict__ pt)
{
  __shared__ float ldsred[128][4];

  const int lane = threadIdx.x & 63;
  const int w    = threadIdx.x >> 6;
  const int wn   = w & 3;
  const int wm   = w >> 2;
  const int ll   = lane & 15;
  const int lq   = lane >> 4;
  const int c0   = blockIdx.x * CT;
  const int rb   = blockIdx.y * 128;         // batch-tile base row
  const int rbase = rb + wm * 64;

  // ---- load this wave's B frags (bf16 in reg) + column sq-norms
  short8 bf[2][4];        // [n][ks]
  float s2[2], qn[2];
#pragma unroll
  for (int n = 0; n < 2; ++n) {
    int c = c0 + wn * 32 + n * 16 + ll;
    const float* rp = praw + (size_t)(c < C_ ? c : C_ - 1) * D_;
    float ss = 0.f;
#pragma unroll
    for (int ks = 0; ks < 4; ++ks) {
      float4 v0 = *(const float4*)(rp + ks * 32 + lq * 8);
      float4 v1 = *(const float4*)(rp + ks * 32 + lq * 8 + 4);
      ss += v0.x * v0.x + v0.y * v0.y + v0.z * v0.z + v0.w * v0.w
          + v1.x * v1.x + v1.y * v1.y + v1.z * v1.z + v1.w * v1.w;
      short8 bb;
      bb[0] = (short)f2b(v0.x); bb[1] = (short)f2b(v0.y);
      bb[2] = (short)f2b(v0.z); bb[3] = (short)f2b(v0.w);
      bb[4] = (short)f2b(v1.x); bb[5] = (short)f2b(v1.y);
      bb[6] = (short)f2b(v1.z); bb[7] = (short)f2b(v1.w);
      bf[n][ks] = bb;
    }
    ss += __shfl_xor(ss, 16);
    ss += __shfl_xor(ss, 32);
    s2[n] = 6.f * LOG2E / fmaxf(sqrtf(ss), 1e-12f);   // log2-units score scale
    qn[n] = (c < C_) ? (-18.f * LOG2E) : -1e30f;      // OOB col -> exp2 = 0
  }

  // ---- MFMA: 64 rows x 32 cols, A-frags hoisted per ks
  f32x4 acc[4][2];
#pragma unroll
  for (int m = 0; m < 4; ++m) {
    acc[m][0] = (f32x4){0.f, 0.f, 0.f, 0.f};
    acc[m][1] = (f32x4){0.f, 0.f, 0.f, 0.f};
  }
#pragma unroll
  for (int ks = 0; ks < 4; ++ks) {
    const int ko = ks * 32 + lq * 8;
    short8 a[4];
#pragma unroll
    for (int m = 0; m < 4; ++m)
      a[m] = *(const short8*)(xnb + (size_t)(rbase + m * 16 + ll) * D_ + ko);
#pragma unroll
    for (int m = 0; m < 4; ++m) {
      acc[m][0] = __builtin_amdgcn_mfma_f32_16x16x32_bf16(a[m], bf[0][ks], acc[m][0], 0, 0, 0);
      acc[m][1] = __builtin_amdgcn_mfma_f32_16x16x32_bf16(a[m], bf[1][ks], acc[m][1], 0, 0, 0);
    }
  }

  // ---- epilogue: exp2 row-sums over this wave's 32 cols; C/D: col=ll, row=lq*4+r
#pragma unroll
  for (int m = 0; m < 4; ++m) {
    float srow[4] = {0.f, 0.f, 0.f, 0.f};
#pragma unroll
    for (int n = 0; n < 2; ++n)
#pragma unroll
      for (int r = 0; r < 4; ++r)
        srow[r] += EXP2F(fmaf(acc[m][n][r], s2[n], qn[n]));
#pragma unroll
    for (int r = 0; r < 4; ++r) {
      float s = srow[r];
      s += __shfl_xor(s, 1);
      s += __shfl_xor(s, 2);
      s += __shfl_xor(s, 4);
      s += __shfl_xor(s, 8);
      if (ll == 0) ldsred[wm * 64 + m * 16 + lq * 4 + r][wn] = s;
    }
  }
  __syncthreads();
  if (threadIdx.x < 128) {
    float s = ldsred[threadIdx.x][0] + ldsred[threadIdx.x][1]
            + ldsred[threadIdx.x][2] + ldsred[threadIdx.x][3];
    // pt layout [g][row]: contiguous 512B per block -> full-line HBM writes
    pt[(size_t)blockIdx.x * B_ + rb + threadIdx.x] = s;
  }
}

// --- kernel E: per-row combine + positive distance + loss ---------------------
__global__ __launch_bounds__(256) void finalize_rows_kernel(
    const float* __restrict__ praw, const unsigned short* __restrict__ xnb,
    const int* __restrict__ labels, const float* __restrict__ pt,
    float* __restrict__ lossb)
{
  int lane = threadIdx.x & 63, wv = threadIdx.x >> 6;
  int row = blockIdx.x * 4 + wv;             // grid=128 -> 512 rows
  int lab = labels[row];
  float2 pv = *(const float2*)(praw + (size_t)lab * D_ + lane * 2);
  ushort2 xv = *(const ushort2*)(xnb + (size_t)row * D_ + lane * 2);
  float xa = b2f(xv.x), xb = b2f(xv.y);
  float ssp = pv.x * pv.x + pv.y * pv.y;
  float dp  = xa * pv.x + xb * pv.y;
#pragma unroll
  for (int off = 32; off; off >>= 1) {
    ssp += __shfl_xor(ssp, off);
    dp  += __shfl_xor(dp, off);
  }
  float pd = 18.f - 2.f * dp * (3.f / fmaxf(sqrtf(ssp), 1e-12f));  // positive dist
  float s = 0.f;
  for (int gg = lane; gg < G_; gg += 64) s += pt[(size_t)gg * B_ + row];
#pragma unroll
  for (int off = 32; off; off >>= 1) s += __shfl_xor(s, off);
  if (lane == 0) lossb[row] = pd + logf(s - __expf(-pd));
}

// --- kernel F: mean over 512 rows ---------------------------------------------
__global__ __launch_bounds__(512) void reduce_mean_kernel(
    const float* __restrict__ lossb, float* __restrict__ out)
{
  int t = threadIdx.x;
  float v = lossb[t];
#pragma unroll
  for (int off = 1; off < 64; off <<= 1) v += __shfl_xor(v, off);
  __shared__ float red[8];
  if ((t & 63) == 0) red[t >> 6] = v;
  __syncthreads();
  if (t == 0) {
    float tot = 0.f;
    for (int i = 0; i < 8; ++i) tot += red[i];
    out[0] = tot / (float)B_;
  }
}

extern "C" void kernel_launch(void* const* d_in, const int* in_sizes, int n_in,
                              void* d_out, int out_size, void* d_ws, size_t ws_size,
                              hipStream_t stream)
{
  const float* batch   = (const float*)d_in[0];
  const int*   labels  = (const int*)d_in[1];
  const float* proxies = (const float*)d_in[2];
  float* out = (float*)d_out;

  unsigned short* xnb = (unsigned short*)d_ws;                   // 512*128*2 = 128KB
  float* pt    = (float*)((char*)d_ws + 131072);                 // 782*512*4 ~= 1.6MB
  float* lossb = (float*)((char*)d_ws + 131072 + (size_t)G_ * B_ * 4);

  batch_norm_kernel<<<B_ / 4, 256, 0, stream>>>(batch, xnb);
  dim3 grid(NBLK, 4);
  pnca_main_kernel<<<grid, 512, 0, stream>>>(proxies, xnb, pt);
  finalize_rows_kernel<<<B_ / 4, 256, 0, stream>>>(proxies, xnb, labels, pt, lossb);
  reduce_mean_kernel<<<1, 512, 0, stream>>>(lossb, out);
}

// Round 5
// 50.937 us; speedup vs baseline: 10.3164x; 2.2888x over previous
//
#include <hip/hip_runtime.h>
#include <math.h>

#define B_ 512
#define C_ 100000
#define D_ 128
#define CT 128                       // proxy cols per block tile
#define NBLK ((C_ + CT - 1) / CT)    // 782 col tiles
#define G_ NBLK
#define LSTR 136                     // LDS row stride (bf16): 272B -> min-conflict frag reads
#define NPAIR ((NBLK + 7) / 8)       // 98
#define MAIN_BLOCKS (NPAIR * 16)     // 98 pairs * 2 halves * 8 xcd slots = 1568
#define LOG2E 1.4426950408889634f

typedef __attribute__((ext_vector_type(8))) short short8;  // 8 bf16 (MFMA A/B frag)
typedef __attribute__((ext_vector_type(4))) float f32x4;   // MFMA C/D frag

__device__ __forceinline__ unsigned short f2b(float x) {  // RNE f32->bf16
  union { float f; unsigned int i; } v; v.f = x;
  unsigned int r = v.i + 0x7FFFu + ((v.i >> 16) & 1u);
  return (unsigned short)(r >> 16);
}
__device__ __forceinline__ float b2f(unsigned short u) {
  union { float f; unsigned int i; } v; v.i = ((unsigned int)u) << 16; return v.f;
}

#if defined(__has_builtin)
#if __has_builtin(__builtin_amdgcn_exp2f)
#define EXP2F(x) __builtin_amdgcn_exp2f(x)
#endif
#endif
#ifndef EXP2F
#define EXP2F(x) __expf(0.69314718055994531f * (x))
#endif

// --- kernel A: normalize batch rows to norm 3, store bf16 ---------------------
__global__ __launch_bounds__(256) void batch_norm_kernel(
    const float* __restrict__ batch, unsigned short* __restrict__ xnb)
{
  int lane = threadIdx.x & 63, wv = threadIdx.x >> 6;
  int r = blockIdx.x * 4 + wv;               // grid=128 -> 512 rows
  float2 v = *(const float2*)(batch + (size_t)r * D_ + lane * 2);
  float ss = v.x * v.x + v.y * v.y;
#pragma unroll
  for (int off = 32; off; off >>= 1) ss += __shfl_xor(ss, off);
  float sc = 3.f / fmaxf(sqrtf(ss), 1e-12f);
  ushort2 o; o.x = f2b(v.x * sc); o.y = f2b(v.y * sc);
  *(ushort2*)(xnb + (size_t)r * D_ + lane * 2) = o;
}

// --- main kernel: LDS-staged proxy tile, A-in-reg, per-lane partial sums ------
// 1568 blocks; block b: xcd slot x=b&7, u=b>>3, half=u&1, coltile=(u>>1)*8+x.
// The two row-halves of a coltile are 8 apart -> same XCD -> 2nd stage hits L2.
// 8 waves x 32 rows = 256 rows per block (half selects which 256 of 512).
__global__ __launch_bounds__(512, 4) void pnca_main_kernel(
    const float* __restrict__ praw, const unsigned short* __restrict__ xnb,
    float* __restrict__ pt)
{
  __shared__ unsigned short plds[CT * LSTR];   // 34816 B, bf16 proxy tile
  __shared__ float scs[CT];                    // per-col ||p||^2 (exact f32)

  const int b = blockIdx.x;
  const int x = b & 7;
  const int u = b >> 3;
  const int half = u & 1;
  const int coltile = (u >> 1) * 8 + x;
  if (coltile >= NBLK) return;                 // uniform across block, pre-barrier
  const int c0 = coltile * CT;

  const int tid  = threadIdx.x;
  const int lane = tid & 63;
  const int w    = tid >> 6;
  const int ll   = lane & 15;
  const int lq   = lane >> 4;

  // ---- stage: each thread owns 4 slots of 8 f32 -> 8 bf16 (issue all loads first)
  float4 va[4][2];
#pragma unroll
  for (int i = 0; i < 4; ++i) {
    int s = i * 512 + tid;                     // 0..2047
    int col = s >> 4, sub = s & 15;
    int c = c0 + col; if (c >= C_) c = C_ - 1;
    const float* rp = praw + (size_t)c * D_ + sub * 8;
    va[i][0] = *(const float4*)(rp);
    va[i][1] = *(const float4*)(rp + 4);
  }
#pragma unroll
  for (int i = 0; i < 4; ++i) {
    int s = i * 512 + tid;
    int col = s >> 4, sub = s & 15;
    float4 v0 = va[i][0], v1 = va[i][1];
    float ss = v0.x*v0.x + v0.y*v0.y + v0.z*v0.z + v0.w*v0.w
             + v1.x*v1.x + v1.y*v1.y + v1.z*v1.z + v1.w*v1.w;
    short8 bb;
    bb[0] = (short)f2b(v0.x); bb[1] = (short)f2b(v0.y);
    bb[2] = (short)f2b(v0.z); bb[3] = (short)f2b(v0.w);
    bb[4] = (short)f2b(v1.x); bb[5] = (short)f2b(v1.y);
    bb[6] = (short)f2b(v1.z); bb[7] = (short)f2b(v1.w);
    *(short8*)(plds + col * LSTR + sub * 8) = bb;
    // 16 threads (sub=0..15) share a col and sit in consecutive lanes
    ss += __shfl_xor(ss, 1);
    ss += __shfl_xor(ss, 2);
    ss += __shfl_xor(ss, 4);
    ss += __shfl_xor(ss, 8);
    if (sub == 0) scs[col] = ss;
  }
  __syncthreads();

  // ---- A frags for this wave's 32 rows (register-resident, from L2-hot xnb)
  const int rbase = half * 256 + w * 32;
  short8 a[2][4];
#pragma unroll
  for (int m = 0; m < 2; ++m)
#pragma unroll
    for (int ks = 0; ks < 4; ++ks)
      a[m][ks] = *(const short8*)(xnb + (size_t)(rbase + m * 16 + ll) * D_ + ks * 32 + lq * 8);

  // ---- loop 8 col-groups of 16; accumulate per-lane partial exp-sums
  float part[2][4];
#pragma unroll
  for (int m = 0; m < 2; ++m)
#pragma unroll
    for (int r = 0; r < 4; ++r) part[m][r] = 0.f;

#pragma unroll
  for (int g = 0; g < 8; ++g) {
    const int colg = g * 16 + ll;
    float ss = scs[colg];
    float s2 = 6.f * LOG2E * __frsqrt_rn(fmaxf(ss, 1e-24f));
    float qn = (c0 + colg < C_) ? (-18.f * LOG2E) : -1e30f;
    short8 bfr[4];
#pragma unroll
    for (int ks = 0; ks < 4; ++ks)
      bfr[ks] = *(const short8*)(plds + colg * LSTR + ks * 32 + lq * 8);
    f32x4 acc0 = (f32x4){0.f, 0.f, 0.f, 0.f};
    f32x4 acc1 = (f32x4){0.f, 0.f, 0.f, 0.f};
#pragma unroll
    for (int ks = 0; ks < 4; ++ks) {
      acc0 = __builtin_amdgcn_mfma_f32_16x16x32_bf16(a[0][ks], bfr[ks], acc0, 0, 0, 0);
      acc1 = __builtin_amdgcn_mfma_f32_16x16x32_bf16(a[1][ks], bfr[ks], acc1, 0, 0, 0);
    }
#pragma unroll
    for (int r = 0; r < 4; ++r) {
      part[0][r] += EXP2F(fmaf(acc0[r], s2, qn));
      part[1][r] += EXP2F(fmaf(acc1[r], s2, qn));
    }
  }

  // ---- one cross-ll (16-lane) reduce per (m,r); write complete block partial
#pragma unroll
  for (int m = 0; m < 2; ++m)
#pragma unroll
    for (int r = 0; r < 4; ++r) {
      float s = part[m][r];
      s += __shfl_xor(s, 1);
      s += __shfl_xor(s, 2);
      s += __shfl_xor(s, 4);
      s += __shfl_xor(s, 8);
      if (ll == 0)
        pt[(size_t)coltile * B_ + rbase + m * 16 + lq * 4 + r] = s;
    }
}

// --- kernel E: per-row combine + positive distance + loss ---------------------
__global__ __launch_bounds__(256) void finalize_rows_kernel(
    const float* __restrict__ praw, const unsigned short* __restrict__ xnb,
    const int* __restrict__ labels, const float* __restrict__ pt,
    float* __restrict__ lossb)
{
  int lane = threadIdx.x & 63, wv = threadIdx.x >> 6;
  int row = blockIdx.x * 4 + wv;             // grid=128 -> 512 rows
  int lab = labels[row];
  float2 pv = *(const float2*)(praw + (size_t)lab * D_ + lane * 2);
  ushort2 xv = *(const ushort2*)(xnb + (size_t)row * D_ + lane * 2);
  float xa = b2f(xv.x), xb = b2f(xv.y);
  float ssp = pv.x * pv.x + pv.y * pv.y;
  float dp  = xa * pv.x + xb * pv.y;
#pragma unroll
  for (int off = 32; off; off >>= 1) {
    ssp += __shfl_xor(ssp, off);
    dp  += __shfl_xor(dp, off);
  }
  float pd = 18.f - 2.f * dp * (3.f / fmaxf(sqrtf(ssp), 1e-12f));  // positive dist
  float s = 0.f;
  for (int gg = lane; gg < G_; gg += 64) s += pt[(size_t)gg * B_ + row];
#pragma unroll
  for (int off = 32; off; off >>= 1) s += __shfl_xor(s, off);
  if (lane == 0) lossb[row] = pd + logf(s - __expf(-pd));
}

// --- kernel F: mean over 512 rows ---------------------------------------------
__global__ __launch_bounds__(512) void reduce_mean_kernel(
    const float* __restrict__ lossb, float* __restrict__ out)
{
  int t = threadIdx.x;
  float v = lossb[t];
#pragma unroll
  for (int off = 1; off < 64; off <<= 1) v += __shfl_xor(v, off);
  __shared__ float red[8];
  if ((t & 63) == 0) red[t >> 6] = v;
  __syncthreads();
  if (t == 0) {
    float tot = 0.f;
    for (int i = 0; i < 8; ++i) tot += red[i];
    out[0] = tot / (float)B_;
  }
}

extern "C" void kernel_launch(void* const* d_in, const int* in_sizes, int n_in,
                              void* d_out, int out_size, void* d_ws, size_t ws_size,
                              hipStream_t stream)
{
  const float* batch   = (const float*)d_in[0];
  const int*   labels  = (const int*)d_in[1];
  const float* proxies = (const float*)d_in[2];
  float* out = (float*)d_out;

  unsigned short* xnb = (unsigned short*)d_ws;                   // 512*128*2 = 128KB
  float* pt    = (float*)((char*)d_ws + 131072);                 // 782*512*4 ~= 1.6MB
  float* lossb = (float*)((char*)d_ws + 131072 + (size_t)G_ * B_ * 4);

  batch_norm_kernel<<<B_ / 4, 256, 0, stream>>>(batch, xnb);
  pnca_main_kernel<<<MAIN_BLOCKS, 512, 0, stream>>>(proxies, xnb, pt);
  finalize_rows_kernel<<<B_ / 4, 256, 0, stream>>>(proxies, xnb, labels, pt, lossb);
  reduce_mean_kernel<<<1, 512, 0, stream>>>(lossb, out);
}